// Round 6
// baseline (595.716 us; speedup 1.0000x reference)
//
#include <hip/hip_runtime.h>
#include <hip/hip_bf16.h>
#include <cstdint>
#include <cstddef>

// MoE dims (fixed by the problem)
#define N_TOK 16384
#define DM    512
#define HD    2048
#define NE    8
#define TOPK  2

// GEMM tiling
#define BM 128
#define BN 128
#define BK 64
#define MAX_TILES 264   // sum ceil(count_e/128), sum count = 32768 -> <= 256+8

// Router: 8 lanes/token (expert-per-lane), 32 tokens per 256-thread block
#define RB_TOK 32

typedef __bf16  bf16x8 __attribute__((ext_vector_type(8)));
typedef float   f32x4  __attribute__((ext_vector_type(4)));

typedef const __attribute__((address_space(1))) void* gas_ptr;
typedef __attribute__((address_space(3))) void*       las_ptr;

__device__ __forceinline__ void async_copy16(const void* g, void* l) {
    __builtin_amdgcn_global_load_lds((gas_ptr)g, (las_ptr)l, 16, 0, 0);
}

// ---------------- init: zero expert counts ----------------------------------
__global__ void k_init(int* __restrict__ count) {
    if (threadIdx.x < NE) count[threadIdx.x] = 0;
}

// ---------------- per-expert transpose + convert: [E][R][C] f32 -> [E][C][R] bf16
__global__ void k_transpose(const float* __restrict__ in, __hip_bfloat16* __restrict__ outp,
                            int R, int C) {
    __shared__ float tile[32][33];
    const int e = blockIdx.z;
    const float* A = in + (size_t)e * R * C;
    __hip_bfloat16* B = outp + (size_t)e * R * C;
    const int c0 = blockIdx.x * 32, r0 = blockIdx.y * 32;
    const int tx = threadIdx.x & 31, ty = threadIdx.x >> 5;   // 32 x 8
#pragma unroll
    for (int i = 0; i < 32; i += 8)
        tile[ty + i][tx] = A[(size_t)(r0 + ty + i) * C + c0 + tx];
    __syncthreads();
#pragma unroll
    for (int i = 0; i < 32; i += 8)
        B[(size_t)(c0 + ty + i) * R + r0 + tx] = __float2bfloat16(tile[tx][ty + i]);
}

// ---------------- router: expert-per-lane, 1 fp64 acc per lane --------------
// Lane j of a token's 8-lane group owns expert j: ONE accumulator per lane
// (no per-lane array -> no spill; R5's acc[8] collapsed to VGPR=24 + scratch).
// Wr in LDS as [e][DM+4]: lane j's float4 read spans banks 4j..4j+3 (+d),
// 8 lanes -> 32 distinct banks, conflict-free, broadcast across groups.
// X phase-2 loads are group-broadcast (8 lanes same addr -> 1 transaction).
__global__ __launch_bounds__(256)
void k_router(const float* __restrict__ X, const float* __restrict__ Wr,
              int* __restrict__ count, int* __restrict__ list,
              int* __restrict__ tokexp, int* __restrict__ tokpos,
              float* __restrict__ tokgate, uint2* __restrict__ Xb4) {
    __shared__ float sWrT[NE][DM + 4];         // 16.5 KB
    const int t = threadIdx.x;
    for (int i = t; i < NE * DM; i += 256) {   // Wr[d][e] -> sWrT[e][d]
        int d = i >> 3, e = i & 7;
        sWrT[e][d] = Wr[i];
    }
    __syncthreads();

    const int grp = t >> 3, j = t & 7;
    const int tok = blockIdx.x * RB_TOK + grp;
    const float4* X4 = (const float4*)X + (size_t)tok * (DM / 4);
    uint2*       xb  = Xb4 + (size_t)tok * (DM / 4);

    // phase 1: fused fp32->bf16 convert; lane j handles float4 j+8k (coalesced)
#pragma unroll
    for (int k = 0; k < DM / 4 / 8; ++k) {
        float4 v = X4[j + 8 * k];
        union { __hip_bfloat16 h[4]; uint2 u; } cv;
        cv.h[0] = __float2bfloat16(v.x);
        cv.h[1] = __float2bfloat16(v.y);
        cv.h[2] = __float2bfloat16(v.z);
        cv.h[3] = __float2bfloat16(v.w);
        xb[j + 8 * k] = cv.u;
    }

    // phase 2: dot(x, Wr[:,j]) in fp64, 4 chain-breaking partials
    double a0 = 0.0, a1 = 0.0, a2 = 0.0, a3 = 0.0;
    const float4* wrow = (const float4*)&sWrT[j][0];
#pragma unroll 8
    for (int i = 0; i < DM / 4; ++i) {
        float4 v = X4[i];                      // broadcast (L1/L2-hot from phase 1)
        float4 w = wrow[i];                    // ds_read_b128, conflict-free
        a0 += (double)v.x * (double)w.x;
        a1 += (double)v.y * (double)w.y;
        a2 += (double)v.z * (double)w.z;
        a3 += (double)v.w * (double)w.w;
    }
    const double acc = (a0 + a1) + (a2 + a3);

    // group max (3 shfl steps)
    double mx = acc;
#pragma unroll
    for (int m = 1; m < 8; m <<= 1) {
        double o = __shfl_xor(mx, m);
        mx = o > mx ? o : mx;
    }
    // group sum of exp (each lane does its own exp -> parallel)
    double sum = exp(acc - mx);
#pragma unroll
    for (int m = 1; m < 8; m <<= 1) sum += __shfl_xor(sum, m);

    // top-2 across the 8-lane group: sorted-pair merge, ties -> lowest index
    double b1v = acc, b2v = -1.0e300;
    int    b1i = j,   b2i = NE;
#pragma unroll
    for (int m = 1; m < 8; m <<= 1) {
        double o1v = __shfl_xor(b1v, m), o2v = __shfl_xor(b2v, m);
        int    o1i = __shfl_xor(b1i, m), o2i = __shfl_xor(b2i, m);
        if (o1v > b1v || (o1v == b1v && o1i < b1i)) {
            b2v = b1v; b2i = b1i;                       // old best1 -> cand 2nd
            if (o2v > b2v || (o2v == b2v && o2i < b2i)) { b2v = o2v; b2i = o2i; }
            b1v = o1v; b1i = o1i;
        } else {
            if (o1v > b2v || (o1v == b2v && o1i < b2i)) { b2v = o1v; b2i = o1i; }
        }
    }

    int i1 = -1, i2 = -1;
    float v1 = 0.f, v2 = 0.f;
    if (j == 0) {
        i1 = b1i; i2 = b2i;
        v1 = (float)(exp(b1v - mx) / sum);
        v2 = (float)(exp(b2v - mx) / sum);
    }

    // wave-aggregated append (lanes with j!=0 have my_e = -1, never match)
    const int lane = t & 63;
#pragma unroll
    for (int k = 0; k < TOPK; ++k) {
        int   my_e = (k == 0) ? i1 : i2;
        float my_v = (k == 0) ? v1 : v2;
        for (int e = 0; e < NE; ++e) {
            unsigned long long msk = __ballot(my_e == e);
            if (!msk) continue;
            int leader = __ffsll(msk) - 1;
            int base = 0;
            if (lane == leader) base = atomicAdd(&count[e], __popcll(msk));
            base = __shfl(base, leader);
            if (my_e == e) {
                int pos = base + __popcll(msk & ((1ull << lane) - 1));
                list[e * N_TOK + pos] = tok;
                tokexp[2 * tok + k]   = e;
                tokpos[2 * tok + k]   = pos;
                tokgate[2 * tok + k]  = my_v;
            }
        }
    }
}

// ---------------- schedule: per-expert tile list + h-row prefix bases -------
__global__ void k_sched(const int* __restrict__ count, int* __restrict__ hbase,
                        int* __restrict__ tileExpert, int* __restrict__ tileRow,
                        int* __restrict__ nTiles) {
    __shared__ int tb[NE + 1];
    const int t = threadIdx.x;                 // 512 threads, 1 block
    if (t == 0) {
        int hb = 0, tc = 0;
        for (int e = 0; e < NE; ++e) {
            hbase[e] = hb;
            tb[e] = tc;
            tc += (count[e] + BM - 1) / BM;
            hb += count[e];
        }
        tb[NE] = tc;
        *nTiles = tc;
    }
    __syncthreads();
    if (t < tb[NE]) {
        int e = 0;
        while (tb[e + 1] <= t) ++e;
        tileExpert[t] = e;
        tileRow[t] = t - tb[e];
    }
}

// XCD-aware swizzle: the NCOL column-tiles of one row-tile get block ids that
// are congruent mod 8 -> same XCD -> the A row-slab is fetched once per XCD.
__device__ __forceinline__ void swizzle_tile(int L, int ncol, int& tile, int& col) {
    tile = (L / (8 * ncol)) * 8 + (L & 7);
    col  = (L >> 3) % ncol;
}

// ---------------- grouped gemm1: h[hb+s,:] = relu(X[tok_s,:] @ W1[e] + b1[e])
// LDS layout XOR-swizzled: row r's global 16B-granule g lives at slot g^(r&7).
__global__ __launch_bounds__(256, 3)
void k_gemm1(const __hip_bfloat16* __restrict__ Xb,
             const __hip_bfloat16* __restrict__ W1bT,
             const float* __restrict__ b1,
             const int* __restrict__ count,
             const int* __restrict__ list,
             const int* __restrict__ hbase,
             const int* __restrict__ tileExpert,
             const int* __restrict__ tileRow,
             const int* __restrict__ nTiles,
             __hip_bfloat16* __restrict__ hbuf) {
    int tile, colT;
    swizzle_tile(blockIdx.x, HD / BN, tile, colT);
    if (tile >= *nTiles) return;
    const int e   = tileExpert[tile];
    const int m0  = tileRow[tile] * BM;
    const int cnt = count[e];
    const int hb  = hbase[e];
    const int n0  = colT * BN;

    __shared__ alignas(16) __hip_bfloat16 As[BM * BK];   // [m][slot], stride 64
    __shared__ alignas(16) __hip_bfloat16 Bs[BN * BK];
    const int t = threadIdx.x;
    const int colg = t & 7;
    const __hip_bfloat16* ag[4];
    const __hip_bfloat16* bg[4];
#pragma unroll
    for (int i = 0; i < 4; ++i) {
        int row = (i * 256 + t) >> 3;                    // 0..127 tile-local
        int gsrc = colg ^ (row & 7);                     // XOR source permutation
        int s = m0 + row; if (s >= cnt) s = cnt - 1;     // clamp tail (no OOB)
        int tok = list[e * N_TOK + s];
        ag[i] = Xb + (size_t)tok * DM + gsrc * 8;
        bg[i] = W1bT + (size_t)e * HD * DM + (size_t)(n0 + row) * DM + gsrc * 8;
    }
    const int lane = t & 63, wave = t >> 6;
    const int wm = (wave & 1) * 64, wn = (wave >> 1) * 64;
    const int lm = lane & 15, quad = lane >> 4;
    f32x4 acc[4][4];
#pragma unroll
    for (int a = 0; a < 4; ++a)
#pragma unroll
        for (int b = 0; b < 4; ++b) acc[a][b] = (f32x4){0.f, 0.f, 0.f, 0.f};

    for (int k0 = 0; k0 < DM; k0 += BK) {
#pragma unroll
        for (int i = 0; i < 4; ++i)
            async_copy16(ag[i] + k0, (char*)As + (i * 256 + t) * 16);
#pragma unroll
        for (int i = 0; i < 4; ++i)
            async_copy16(bg[i] + k0, (char*)Bs + (i * 256 + t) * 16);
        __syncthreads();
#pragma unroll
        for (int kk = 0; kk < BK; kk += 32) {
            bf16x8 av[4], bv[4];
#pragma unroll
            for (int mt = 0; mt < 4; ++mt) {
                int r = wm + mt * 16 + lm, g = (kk >> 3) + quad;
                av[mt] = *(const bf16x8*)(As + r * BK + ((g ^ (r & 7)) << 3));
            }
#pragma unroll
            for (int nt = 0; nt < 4; ++nt) {
                int r = wn + nt * 16 + lm, g = (kk >> 3) + quad;
                bv[nt] = *(const bf16x8*)(Bs + r * BK + ((g ^ (r & 7)) << 3));
            }
#pragma unroll
            for (int mt = 0; mt < 4; ++mt)
#pragma unroll
                for (int nt = 0; nt < 4; ++nt)
                    acc[mt][nt] = __builtin_amdgcn_mfma_f32_16x16x32_bf16(
                        av[mt], bv[nt], acc[mt][nt], 0, 0, 0);
        }
        __syncthreads();
    }
    // epilogue: bias + relu -> bf16 h at global slot hb+s
#pragma unroll
    for (int mt = 0; mt < 4; ++mt) {
#pragma unroll
        for (int r = 0; r < 4; ++r) {
            int s = m0 + wm + mt * 16 + quad * 4 + r;
            if (s < cnt) {
                __hip_bfloat16* hrow = hbuf + (size_t)(hb + s) * HD;
#pragma unroll
                for (int nt = 0; nt < 4; ++nt) {
                    int hc = n0 + wn + nt * 16 + lm;
                    float v = acc[mt][nt][r] + b1[e * HD + hc];
                    hrow[hc] = __float2bfloat16(fmaxf(v, 0.f));
                }
            }
        }
    }
}

// ---------------- grouped gemm2: y[hb+s,:] = h[hb+s,:] @ W2[e] + b2[e] ------
// No gather, no atomics: slot-contiguous bf16 stores; combine pass applies gates.
__global__ __launch_bounds__(256, 3)
void k_gemm2(const __hip_bfloat16* __restrict__ hbuf,
             const __hip_bfloat16* __restrict__ W2bT,
             const float* __restrict__ b2,
             const int* __restrict__ count,
             const int* __restrict__ hbase,
             const int* __restrict__ tileExpert,
             const int* __restrict__ tileRow,
             const int* __restrict__ nTiles,
             __hip_bfloat16* __restrict__ yb) {
    int tile, colT;
    swizzle_tile(blockIdx.x, DM / BN, tile, colT);
    if (tile >= *nTiles) return;
    const int e   = tileExpert[tile];
    const int m0  = tileRow[tile] * BM;
    const int cnt = count[e];
    const int hb  = hbase[e];
    const int n0  = colT * BN;

    __shared__ alignas(16) __hip_bfloat16 As[BM * BK];
    __shared__ alignas(16) __hip_bfloat16 Bs[BN * BK];
    const int t = threadIdx.x;
    const int colg = t & 7;
    const __hip_bfloat16* ag[4];
    const __hip_bfloat16* bg[4];
#pragma unroll
    for (int i = 0; i < 4; ++i) {
        int row = (i * 256 + t) >> 3;
        int gsrc = colg ^ (row & 7);
        int s = m0 + row; if (s >= cnt) s = cnt - 1;
        ag[i] = hbuf + (size_t)(hb + s) * HD + gsrc * 8;
        bg[i] = W2bT + (size_t)e * DM * HD + (size_t)(n0 + row) * HD + gsrc * 8;
    }
    const int lane = t & 63, wave = t >> 6;
    const int wm = (wave & 1) * 64, wn = (wave >> 1) * 64;
    const int lm = lane & 15, quad = lane >> 4;
    f32x4 acc[4][4];
#pragma unroll
    for (int a = 0; a < 4; ++a)
#pragma unroll
        for (int b = 0; b < 4; ++b) acc[a][b] = (f32x4){0.f, 0.f, 0.f, 0.f};

    for (int k0 = 0; k0 < HD; k0 += BK) {
#pragma unroll
        for (int i = 0; i < 4; ++i)
            async_copy16(ag[i] + k0, (char*)As + (i * 256 + t) * 16);
#pragma unroll
        for (int i = 0; i < 4; ++i)
            async_copy16(bg[i] + k0, (char*)Bs + (i * 256 + t) * 16);
        __syncthreads();
#pragma unroll
        for (int kk = 0; kk < BK; kk += 32) {
            bf16x8 av[4], bv[4];
#pragma unroll
            for (int mt = 0; mt < 4; ++mt) {
                int r = wm + mt * 16 + lm, g = (kk >> 3) + quad;
                av[mt] = *(const bf16x8*)(As + r * BK + ((g ^ (r & 7)) << 3));
            }
#pragma unroll
            for (int nt = 0; nt < 4; ++nt) {
                int r = wn + nt * 16 + lm, g = (kk >> 3) + quad;
                bv[nt] = *(const bf16x8*)(Bs + r * BK + ((g ^ (r & 7)) << 3));
            }
#pragma unroll
            for (int mt = 0; mt < 4; ++mt)
#pragma unroll
                for (int nt = 0; nt < 4; ++nt)
                    acc[mt][nt] = __builtin_amdgcn_mfma_f32_16x16x32_bf16(
                        av[mt], bv[nt], acc[mt][nt], 0, 0, 0);
        }
        __syncthreads();
    }
    // epilogue: y = acc + b2 (bias folded here), bf16 streaming store
#pragma unroll
    for (int mt = 0; mt < 4; ++mt) {
#pragma unroll
        for (int r = 0; r < 4; ++r) {
            int s = m0 + wm + mt * 16 + quad * 4 + r;
            if (s < cnt) {
                __hip_bfloat16* yrow = yb + (size_t)(hb + s) * DM;
#pragma unroll
                for (int nt = 0; nt < 4; ++nt) {
                    int dc = n0 + wn + nt * 16 + lm;
                    yrow[dc] = __float2bfloat16(acc[mt][nt][r] + b2[e * DM + dc]);
                }
            }
        }
    }
}

// ---------------- combine: out[n,:] = g1*y[slot1,:] + g2*y[slot2,:] ---------
__global__ __launch_bounds__(256)
void k_combine(const __hip_bfloat16* __restrict__ yb,
               const int* __restrict__ hbase,
               const int* __restrict__ tokexp,
               const int* __restrict__ tokpos,
               const float* __restrict__ tokgate,
               float* __restrict__ out) {
    const int n = blockIdx.x * 4 + (threadIdx.x >> 6);   // wave per token
    const int lane = threadIdx.x & 63;
    const int s1 = hbase[tokexp[2 * n]]     + tokpos[2 * n];
    const int s2 = hbase[tokexp[2 * n + 1]] + tokpos[2 * n + 1];
    const float g1 = tokgate[2 * n], g2 = tokgate[2 * n + 1];
    uint4 a = ((const uint4*)(yb + (size_t)s1 * DM))[lane];   // 8 bf16
    uint4 b = ((const uint4*)(yb + (size_t)s2 * DM))[lane];
    float o[8];
    const unsigned* au = (const unsigned*)&a;
    const unsigned* bu = (const unsigned*)&b;
#pragma unroll
    for (int j = 0; j < 4; ++j) {
        union { unsigned u; float f; } alo, ahi, blo, bhi;
        alo.u = au[j] << 16; ahi.u = au[j] & 0xFFFF0000u;
        blo.u = bu[j] << 16; bhi.u = bu[j] & 0xFFFF0000u;
        o[2 * j]     = g1 * alo.f + g2 * blo.f;
        o[2 * j + 1] = g1 * ahi.f + g2 * bhi.f;
    }
    float4* orow = (float4*)(out + (size_t)n * DM);
    orow[lane * 2]     = make_float4(o[0], o[1], o[2], o[3]);
    orow[lane * 2 + 1] = make_float4(o[4], o[5], o[6], o[7]);
    if (blockIdx.x == 0 && threadIdx.x == 0) out[(size_t)N_TOK * DM] = 0.f;  // loss
}

// ---------------- launch ----------------------------------------------------
extern "C" void kernel_launch(void* const* d_in, const int* in_sizes, int n_in,
                              void* d_out, int out_size, void* d_ws, size_t ws_size,
                              hipStream_t stream) {
    const float* X  = (const float*)d_in[0];
    const float* Wr = (const float*)d_in[1];
    const float* W1 = (const float*)d_in[2];
    const float* b1 = (const float*)d_in[3];
    const float* W2 = (const float*)d_in[4];
    const float* b2 = (const float*)d_in[5];
    float* out = (float*)d_out;

    // workspace layout (bytes). yb aliases Xb+W1bT: both dead once gemm1 completes
    // (stream-ordered before gemm2 writes yb).
    char* ws = (char*)d_ws;
    __hip_bfloat16* Xb   = (__hip_bfloat16*)(ws + 0);          // N*D*2        = 16,777,216
    __hip_bfloat16* W1bT = (__hip_bfloat16*)(ws + 16777216);   // E*H*D*2      = 16,777,216
    __hip_bfloat16* yb   = (__hip_bfloat16*)(ws + 0);          // 32K*D*2      = 33,554,432 (alias)
    __hip_bfloat16* W2bT = (__hip_bfloat16*)(ws + 33554432);   // E*D*H*2      = 16,777,216
    __hip_bfloat16* hbuf = (__hip_bfloat16*)(ws + 50331648);   // N*K*H*2      = 134,217,728
    int*   list   = (int*)  (ws + 184549376);                  // E*N*4        = 524,288
    int*   tokexp = (int*)  (ws + 185073664);                  // N*2*4        = 131,072
    int*   tokpos = (int*)  (ws + 185204736);                  // 131,072
    float* tokgate= (float*)(ws + 185335808);                  // 131,072
    int*   count  = (int*)  (ws + 185466880);                  // 32
    int*   hbase  = (int*)  (ws + 185466944);                  // 32
    int*   tileE  = (int*)  (ws + 185467008);                  // 1088
    int*   tileR  = (int*)  (ws + 185468096);                  // 1088
    int*   nTil   = (int*)  (ws + 185469184);                  // 4

    k_init<<<dim3(1), 64, 0, stream>>>(count);
    k_transpose<<<dim3(HD / 32, DM / 32, NE), 256, 0, stream>>>(W1, W1bT, DM, HD);
    k_transpose<<<dim3(DM / 32, HD / 32, NE), 256, 0, stream>>>(W2, W2bT, HD, DM);
    k_router<<<dim3(N_TOK / RB_TOK), 256, 0, stream>>>(X, Wr, count, list,
                                                       tokexp, tokpos, tokgate, (uint2*)Xb);
    k_sched<<<dim3(1), 512, 0, stream>>>(count, hbase, tileE, tileR, nTil);
    k_gemm1<<<dim3(MAX_TILES * (HD / BN)), 256, 0, stream>>>(Xb, W1bT, b1, count, list,
                                                             hbase, tileE, tileR, nTil, hbuf);
    k_gemm2<<<dim3(MAX_TILES * (DM / BN)), 256, 0, stream>>>(hbuf, W2bT, b2, count,
                                                             hbase, tileE, tileR, nTil, yb);
    k_combine<<<dim3(N_TOK / 4), 256, 0, stream>>>(yb, hbase, tokexp, tokpos, tokgate, out);
}

// Round 7
// 353.814 us; speedup vs baseline: 1.6837x; 1.6837x over previous
//
#include <hip/hip_runtime.h>
#include <hip/hip_bf16.h>
#include <cstdint>
#include <cstddef>

// MoE dims (fixed by the problem)
#define N_TOK 16384
#define DM    512
#define HD    2048
#define NE    8
#define TOPK  2

// GEMM tiling
#define BM 128
#define BN 128
#define BK 64
#define MAX_TILES 264   // sum ceil(count_e/128), sum count = 32768 -> <= 256+8

// Router: 8 lanes/token (expert-per-lane), 32 tokens per 256-thread block
#define RB_TOK 32

// count[] is padded to one 64B L2 line per expert: count[e*CSTRIDE]
#define CSTRIDE 16

typedef __bf16  bf16x8 __attribute__((ext_vector_type(8)));
typedef float   f32x4  __attribute__((ext_vector_type(4)));

typedef const __attribute__((address_space(1))) void* gas_ptr;
typedef __attribute__((address_space(3))) void*       las_ptr;

__device__ __forceinline__ void async_copy16(const void* g, void* l) {
    __builtin_amdgcn_global_load_lds((gas_ptr)g, (las_ptr)l, 16, 0, 0);
}

// ---------------- init: zero padded expert counters --------------------------
__global__ void k_init(int* __restrict__ count) {
    if (threadIdx.x < NE * CSTRIDE) count[threadIdx.x] = 0;
}

// ---------------- per-expert transpose + convert: [E][R][C] f32 -> [E][C][R] bf16
__global__ void k_transpose(const float* __restrict__ in, __hip_bfloat16* __restrict__ outp,
                            int R, int C) {
    __shared__ float tile[32][33];
    const int e = blockIdx.z;
    const float* A = in + (size_t)e * R * C;
    __hip_bfloat16* B = outp + (size_t)e * R * C;
    const int c0 = blockIdx.x * 32, r0 = blockIdx.y * 32;
    const int tx = threadIdx.x & 31, ty = threadIdx.x >> 5;   // 32 x 8
#pragma unroll
    for (int i = 0; i < 32; i += 8)
        tile[ty + i][tx] = A[(size_t)(r0 + ty + i) * C + c0 + tx];
    __syncthreads();
#pragma unroll
    for (int i = 0; i < 32; i += 8)
        B[(size_t)(c0 + ty + i) * R + r0 + tx] = __float2bfloat16(tile[tx][ty + i]);
}

// ---------------- router: expert-per-lane compute + block-aggregated append -
// Compute identical to R6 (verified). Append rebuilt: the old wave-level
// ballot append issued ~22K serialized value-returning atomics, ALL on one
// 32B L2 line -> ~280 us of line-serialized RMW (R1/R5/R6 all ~275-380 us
// regardless of compute). Now: LDS atomics for intra-block positions, then
// 8 global atomics per block (one wave round) on 64B-strided counters.
__global__ __launch_bounds__(256)
void k_router(const float* __restrict__ X, const float* __restrict__ Wr,
              int* __restrict__ count, int* __restrict__ list,
              int* __restrict__ tokexp, int* __restrict__ tokpos,
              float* __restrict__ tokgate, uint2* __restrict__ Xb4) {
    __shared__ float sWrT[NE][DM + 4];         // 16.5 KB
    __shared__ int lcnt[NE];
    __shared__ int gbase[NE];
    const int t = threadIdx.x;
    for (int i = t; i < NE * DM; i += 256) {   // Wr[d][e] -> sWrT[e][d]
        int d = i >> 3, e = i & 7;
        sWrT[e][d] = Wr[i];
    }
    if (t < NE) lcnt[t] = 0;
    __syncthreads();

    const int grp = t >> 3, j = t & 7;
    const int tok = blockIdx.x * RB_TOK + grp;
    const float4* X4 = (const float4*)X + (size_t)tok * (DM / 4);
    uint2*       xb  = Xb4 + (size_t)tok * (DM / 4);

    // phase 1: fused fp32->bf16 convert; lane j handles float4 j+8k (coalesced)
#pragma unroll
    for (int k = 0; k < DM / 4 / 8; ++k) {
        float4 v = X4[j + 8 * k];
        union { __hip_bfloat16 h[4]; uint2 u; } cv;
        cv.h[0] = __float2bfloat16(v.x);
        cv.h[1] = __float2bfloat16(v.y);
        cv.h[2] = __float2bfloat16(v.z);
        cv.h[3] = __float2bfloat16(v.w);
        xb[j + 8 * k] = cv.u;
    }

    // phase 2: dot(x, Wr[:,j]) in fp64, 4 chain-breaking partials
    double a0 = 0.0, a1 = 0.0, a2 = 0.0, a3 = 0.0;
    const float4* wrow = (const float4*)&sWrT[j][0];
#pragma unroll 8
    for (int i = 0; i < DM / 4; ++i) {
        float4 v = X4[i];                      // broadcast (L1/L2-hot from phase 1)
        float4 w = wrow[i];                    // ds_read_b128, conflict-free
        a0 += (double)v.x * (double)w.x;
        a1 += (double)v.y * (double)w.y;
        a2 += (double)v.z * (double)w.z;
        a3 += (double)v.w * (double)w.w;
    }
    const double acc = (a0 + a1) + (a2 + a3);

    // group max (3 shfl steps)
    double mx = acc;
#pragma unroll
    for (int m = 1; m < 8; m <<= 1) {
        double o = __shfl_xor(mx, m);
        mx = o > mx ? o : mx;
    }
    // group sum of exp (each lane does its own exp -> parallel)
    double sum = exp(acc - mx);
#pragma unroll
    for (int m = 1; m < 8; m <<= 1) sum += __shfl_xor(sum, m);

    // top-2 across the 8-lane group: sorted-pair merge, ties -> lowest index
    double b1v = acc, b2v = -1.0e300;
    int    b1i = j,   b2i = NE;
#pragma unroll
    for (int m = 1; m < 8; m <<= 1) {
        double o1v = __shfl_xor(b1v, m), o2v = __shfl_xor(b2v, m);
        int    o1i = __shfl_xor(b1i, m), o2i = __shfl_xor(b2i, m);
        if (o1v > b1v || (o1v == b1v && o1i < b1i)) {
            b2v = b1v; b2i = b1i;                       // old best1 -> cand 2nd
            if (o2v > b2v || (o2v == b2v && o2i < b2i)) { b2v = o2v; b2i = o2i; }
            b1v = o1v; b1i = o1i;
        } else {
            if (o1v > b2v || (o1v == b2v && o1i < b2i)) { b2v = o1v; b2i = o1i; }
        }
    }

    // intra-block positions via LDS atomics (per-CU, cheap)
    int lp1 = 0, lp2 = 0;
    if (j == 0) {
        lp1 = atomicAdd(&lcnt[b1i], 1);
        lp2 = atomicAdd(&lcnt[b2i], 1);
    }
    __syncthreads();
    // one wave-round of global atomics: 8 lanes -> 8 distinct 64B lines
    if (t < NE) gbase[t] = atomicAdd(&count[t * CSTRIDE], lcnt[t]);
    __syncthreads();

    if (j == 0) {
        float v1 = (float)(exp(b1v - mx) / sum);
        float v2 = (float)(exp(b2v - mx) / sum);
        int p1 = gbase[b1i] + lp1;
        int p2 = gbase[b2i] + lp2;
        list[b1i * N_TOK + p1] = tok;
        list[b2i * N_TOK + p2] = tok;
        tokexp[2 * tok]     = b1i;  tokexp[2 * tok + 1]  = b2i;
        tokpos[2 * tok]     = p1;   tokpos[2 * tok + 1]  = p2;
        tokgate[2 * tok]    = v1;   tokgate[2 * tok + 1] = v2;
    }
}

// ---------------- schedule: per-expert tile list + h-row prefix bases -------
__global__ void k_sched(const int* __restrict__ count, int* __restrict__ hbase,
                        int* __restrict__ tileExpert, int* __restrict__ tileRow,
                        int* __restrict__ nTiles) {
    __shared__ int tb[NE + 1];
    const int t = threadIdx.x;                 // 512 threads, 1 block
    if (t == 0) {
        int hb = 0, tc = 0;
        for (int e = 0; e < NE; ++e) {
            hbase[e] = hb;
            tb[e] = tc;
            tc += (count[e * CSTRIDE] + BM - 1) / BM;
            hb += count[e * CSTRIDE];
        }
        tb[NE] = tc;
        *nTiles = tc;
    }
    __syncthreads();
    if (t < tb[NE]) {
        int e = 0;
        while (tb[e + 1] <= t) ++e;
        tileExpert[t] = e;
        tileRow[t] = t - tb[e];
    }
}

// XCD-aware swizzle: the NCOL column-tiles of one row-tile get block ids that
// are congruent mod 8 -> same XCD -> the A row-slab is fetched once per XCD.
__device__ __forceinline__ void swizzle_tile(int L, int ncol, int& tile, int& col) {
    tile = (L / (8 * ncol)) * 8 + (L & 7);
    col  = (L >> 3) % ncol;
}

// ---------------- grouped gemm1: h[hb+s,:] = relu(X[tok_s,:] @ W1[e] + b1[e])
// LDS layout XOR-swizzled: row r's global 16B-granule g lives at slot g^(r&7).
__global__ __launch_bounds__(256, 3)
void k_gemm1(const __hip_bfloat16* __restrict__ Xb,
             const __hip_bfloat16* __restrict__ W1bT,
             const float* __restrict__ b1,
             const int* __restrict__ count,
             const int* __restrict__ list,
             const int* __restrict__ hbase,
             const int* __restrict__ tileExpert,
             const int* __restrict__ tileRow,
             const int* __restrict__ nTiles,
             __hip_bfloat16* __restrict__ hbuf) {
    int tile, colT;
    swizzle_tile(blockIdx.x, HD / BN, tile, colT);
    if (tile >= *nTiles) return;
    const int e   = tileExpert[tile];
    const int m0  = tileRow[tile] * BM;
    const int cnt = count[e * CSTRIDE];
    const int hb  = hbase[e];
    const int n0  = colT * BN;

    __shared__ alignas(16) __hip_bfloat16 As[BM * BK];   // [m][slot], stride 64
    __shared__ alignas(16) __hip_bfloat16 Bs[BN * BK];
    const int t = threadIdx.x;
    const int colg = t & 7;
    const __hip_bfloat16* ag[4];
    const __hip_bfloat16* bg[4];
#pragma unroll
    for (int i = 0; i < 4; ++i) {
        int row = (i * 256 + t) >> 3;                    // 0..127 tile-local
        int gsrc = colg ^ (row & 7);                     // XOR source permutation
        int s = m0 + row; if (s >= cnt) s = cnt - 1;     // clamp tail (no OOB)
        int tok = list[e * N_TOK + s];
        ag[i] = Xb + (size_t)tok * DM + gsrc * 8;
        bg[i] = W1bT + (size_t)e * HD * DM + (size_t)(n0 + row) * DM + gsrc * 8;
    }
    const int lane = t & 63, wave = t >> 6;
    const int wm = (wave & 1) * 64, wn = (wave >> 1) * 64;
    const int lm = lane & 15, quad = lane >> 4;
    f32x4 acc[4][4];
#pragma unroll
    for (int a = 0; a < 4; ++a)
#pragma unroll
        for (int b = 0; b < 4; ++b) acc[a][b] = (f32x4){0.f, 0.f, 0.f, 0.f};

    for (int k0 = 0; k0 < DM; k0 += BK) {
#pragma unroll
        for (int i = 0; i < 4; ++i)
            async_copy16(ag[i] + k0, (char*)As + (i * 256 + t) * 16);
#pragma unroll
        for (int i = 0; i < 4; ++i)
            async_copy16(bg[i] + k0, (char*)Bs + (i * 256 + t) * 16);
        __syncthreads();
#pragma unroll
        for (int kk = 0; kk < BK; kk += 32) {
            bf16x8 av[4], bv[4];
#pragma unroll
            for (int mt = 0; mt < 4; ++mt) {
                int r = wm + mt * 16 + lm, g = (kk >> 3) + quad;
                av[mt] = *(const bf16x8*)(As + r * BK + ((g ^ (r & 7)) << 3));
            }
#pragma unroll
            for (int nt = 0; nt < 4; ++nt) {
                int r = wn + nt * 16 + lm, g = (kk >> 3) + quad;
                bv[nt] = *(const bf16x8*)(Bs + r * BK + ((g ^ (r & 7)) << 3));
            }
#pragma unroll
            for (int mt = 0; mt < 4; ++mt)
#pragma unroll
                for (int nt = 0; nt < 4; ++nt)
                    acc[mt][nt] = __builtin_amdgcn_mfma_f32_16x16x32_bf16(
                        av[mt], bv[nt], acc[mt][nt], 0, 0, 0);
        }
        __syncthreads();
    }
    // epilogue: bias + relu -> bf16 h at global slot hb+s
#pragma unroll
    for (int mt = 0; mt < 4; ++mt) {
#pragma unroll
        for (int r = 0; r < 4; ++r) {
            int s = m0 + wm + mt * 16 + quad * 4 + r;
            if (s < cnt) {
                __hip_bfloat16* hrow = hbuf + (size_t)(hb + s) * HD;
#pragma unroll
                for (int nt = 0; nt < 4; ++nt) {
                    int hc = n0 + wn + nt * 16 + lm;
                    float v = acc[mt][nt][r] + b1[e * HD + hc];
                    hrow[hc] = __float2bfloat16(fmaxf(v, 0.f));
                }
            }
        }
    }
}

// ---------------- grouped gemm2: y[hb+s,:] = h[hb+s,:] @ W2[e] + b2[e] ------
// No gather, no atomics: slot-contiguous bf16 stores; combine pass applies gates.
__global__ __launch_bounds__(256, 3)
void k_gemm2(const __hip_bfloat16* __restrict__ hbuf,
             const __hip_bfloat16* __restrict__ W2bT,
             const float* __restrict__ b2,
             const int* __restrict__ count,
             const int* __restrict__ hbase,
             const int* __restrict__ tileExpert,
             const int* __restrict__ tileRow,
             const int* __restrict__ nTiles,
             __hip_bfloat16* __restrict__ yb) {
    int tile, colT;
    swizzle_tile(blockIdx.x, DM / BN, tile, colT);
    if (tile >= *nTiles) return;
    const int e   = tileExpert[tile];
    const int m0  = tileRow[tile] * BM;
    const int cnt = count[e * CSTRIDE];
    const int hb  = hbase[e];
    const int n0  = colT * BN;

    __shared__ alignas(16) __hip_bfloat16 As[BM * BK];
    __shared__ alignas(16) __hip_bfloat16 Bs[BN * BK];
    const int t = threadIdx.x;
    const int colg = t & 7;
    const __hip_bfloat16* ag[4];
    const __hip_bfloat16* bg[4];
#pragma unroll
    for (int i = 0; i < 4; ++i) {
        int row = (i * 256 + t) >> 3;
        int gsrc = colg ^ (row & 7);
        int s = m0 + row; if (s >= cnt) s = cnt - 1;
        ag[i] = hbuf + (size_t)(hb + s) * HD + gsrc * 8;
        bg[i] = W2bT + (size_t)e * DM * HD + (size_t)(n0 + row) * HD + gsrc * 8;
    }
    const int lane = t & 63, wave = t >> 6;
    const int wm = (wave & 1) * 64, wn = (wave >> 1) * 64;
    const int lm = lane & 15, quad = lane >> 4;
    f32x4 acc[4][4];
#pragma unroll
    for (int a = 0; a < 4; ++a)
#pragma unroll
        for (int b = 0; b < 4; ++b) acc[a][b] = (f32x4){0.f, 0.f, 0.f, 0.f};

    for (int k0 = 0; k0 < HD; k0 += BK) {
#pragma unroll
        for (int i = 0; i < 4; ++i)
            async_copy16(ag[i] + k0, (char*)As + (i * 256 + t) * 16);
#pragma unroll
        for (int i = 0; i < 4; ++i)
            async_copy16(bg[i] + k0, (char*)Bs + (i * 256 + t) * 16);
        __syncthreads();
#pragma unroll
        for (int kk = 0; kk < BK; kk += 32) {
            bf16x8 av[4], bv[4];
#pragma unroll
            for (int mt = 0; mt < 4; ++mt) {
                int r = wm + mt * 16 + lm, g = (kk >> 3) + quad;
                av[mt] = *(const bf16x8*)(As + r * BK + ((g ^ (r & 7)) << 3));
            }
#pragma unroll
            for (int nt = 0; nt < 4; ++nt) {
                int r = wn + nt * 16 + lm, g = (kk >> 3) + quad;
                bv[nt] = *(const bf16x8*)(Bs + r * BK + ((g ^ (r & 7)) << 3));
            }
#pragma unroll
            for (int mt = 0; mt < 4; ++mt)
#pragma unroll
                for (int nt = 0; nt < 4; ++nt)
                    acc[mt][nt] = __builtin_amdgcn_mfma_f32_16x16x32_bf16(
                        av[mt], bv[nt], acc[mt][nt], 0, 0, 0);
        }
        __syncthreads();
    }
    // epilogue: y = acc + b2 (bias folded here), bf16 streaming store
#pragma unroll
    for (int mt = 0; mt < 4; ++mt) {
#pragma unroll
        for (int r = 0; r < 4; ++r) {
            int s = m0 + wm + mt * 16 + quad * 4 + r;
            if (s < cnt) {
                __hip_bfloat16* yrow = yb + (size_t)(hb + s) * DM;
#pragma unroll
                for (int nt = 0; nt < 4; ++nt) {
                    int dc = n0 + wn + nt * 16 + lm;
                    yrow[dc] = __float2bfloat16(acc[mt][nt][r] + b2[e * DM + dc]);
                }
            }
        }
    }
}

// ---------------- combine: out[n,:] = g1*y[slot1,:] + g2*y[slot2,:] ---------
__global__ __launch_bounds__(256)
void k_combine(const __hip_bfloat16* __restrict__ yb,
               const int* __restrict__ hbase,
               const int* __restrict__ tokexp,
               const int* __restrict__ tokpos,
               const float* __restrict__ tokgate,
               float* __restrict__ out) {
    const int n = blockIdx.x * 4 + (threadIdx.x >> 6);   // wave per token
    const int lane = threadIdx.x & 63;
    const int s1 = hbase[tokexp[2 * n]]     + tokpos[2 * n];
    const int s2 = hbase[tokexp[2 * n + 1]] + tokpos[2 * n + 1];
    const float g1 = tokgate[2 * n], g2 = tokgate[2 * n + 1];
    uint4 a = ((const uint4*)(yb + (size_t)s1 * DM))[lane];   // 8 bf16
    uint4 b = ((const uint4*)(yb + (size_t)s2 * DM))[lane];
    float o[8];
    const unsigned* au = (const unsigned*)&a;
    const unsigned* bu = (const unsigned*)&b;
#pragma unroll
    for (int j = 0; j < 4; ++j) {
        union { unsigned u; float f; } alo, ahi, blo, bhi;
        alo.u = au[j] << 16; ahi.u = au[j] & 0xFFFF0000u;
        blo.u = bu[j] << 16; bhi.u = bu[j] & 0xFFFF0000u;
        o[2 * j]     = g1 * alo.f + g2 * blo.f;
        o[2 * j + 1] = g1 * ahi.f + g2 * bhi.f;
    }
    float4* orow = (float4*)(out + (size_t)n * DM);
    orow[lane * 2]     = make_float4(o[0], o[1], o[2], o[3]);
    orow[lane * 2 + 1] = make_float4(o[4], o[5], o[6], o[7]);
    if (blockIdx.x == 0 && threadIdx.x == 0) out[(size_t)N_TOK * DM] = 0.f;  // loss
}

// ---------------- launch ----------------------------------------------------
extern "C" void kernel_launch(void* const* d_in, const int* in_sizes, int n_in,
                              void* d_out, int out_size, void* d_ws, size_t ws_size,
                              hipStream_t stream) {
    const float* X  = (const float*)d_in[0];
    const float* Wr = (const float*)d_in[1];
    const float* W1 = (const float*)d_in[2];
    const float* b1 = (const float*)d_in[3];
    const float* W2 = (const float*)d_in[4];
    const float* b2 = (const float*)d_in[5];
    float* out = (float*)d_out;

    // workspace layout (bytes). yb aliases Xb+W1bT: both dead once gemm1 completes
    // (stream-ordered before gemm2 writes yb).
    char* ws = (char*)d_ws;
    __hip_bfloat16* Xb   = (__hip_bfloat16*)(ws + 0);          // N*D*2        = 16,777,216
    __hip_bfloat16* W1bT = (__hip_bfloat16*)(ws + 16777216);   // E*H*D*2      = 16,777,216
    __hip_bfloat16* yb   = (__hip_bfloat16*)(ws + 0);          // 32K*D*2      = 33,554,432 (alias)
    __hip_bfloat16* W2bT = (__hip_bfloat16*)(ws + 33554432);   // E*D*H*2      = 16,777,216
    __hip_bfloat16* hbuf = (__hip_bfloat16*)(ws + 50331648);   // N*K*H*2      = 134,217,728
    int*   list   = (int*)  (ws + 184549376);                  // E*N*4        = 524,288
    int*   tokexp = (int*)  (ws + 185073664);                  // N*2*4        = 131,072
    int*   tokpos = (int*)  (ws + 185204736);                  // 131,072
    float* tokgate= (float*)(ws + 185335808);                  // 131,072
    int*   count  = (int*)  (ws + 185466880);                  // 8*16*4 = 512 (64B/expert)
    int*   hbase  = (int*)  (ws + 185467392);                  // 32
    int*   tileE  = (int*)  (ws + 185467456);                  // 1088
    int*   tileR  = (int*)  (ws + 185468544);                  // 1088
    int*   nTil   = (int*)  (ws + 185469632);                  // 4

    k_init<<<dim3(1), 256, 0, stream>>>(count);
    k_transpose<<<dim3(HD / 32, DM / 32, NE), 256, 0, stream>>>(W1, W1bT, DM, HD);
    k_transpose<<<dim3(DM / 32, HD / 32, NE), 256, 0, stream>>>(W2, W2bT, HD, DM);
    k_router<<<dim3(N_TOK / RB_TOK), 256, 0, stream>>>(X, Wr, count, list,
                                                       tokexp, tokpos, tokgate, (uint2*)Xb);
    k_sched<<<dim3(1), 512, 0, stream>>>(count, hbase, tileE, tileR, nTil);
    k_gemm1<<<dim3(MAX_TILES * (HD / BN)), 256, 0, stream>>>(Xb, W1bT, b1, count, list,
                                                             hbase, tileE, tileR, nTil, hbuf);
    k_gemm2<<<dim3(MAX_TILES * (DM / BN)), 256, 0, stream>>>(hbuf, W2bT, b2, count,
                                                             hbase, tileE, tileR, nTil, yb);
    k_combine<<<dim3(N_TOK / 4), 256, 0, stream>>>(yb, hbase, tokexp, tokpos, tokgate, out);
}